// Round 5
// baseline (217.902 us; speedup 1.0000x reference)
//
#include <hip/hip_runtime.h>
#include <hip/hip_bf16.h>
#include <cstdint>
#include <cstddef>

#define B_SZ 4
#define T_SZ 1024
#define N_SZ 1024
#define HID 1024
#define NHEADS 16
#define DHEAD 64

typedef __bf16 bf16x8 __attribute__((ext_vector_type(8)));
typedef __bf16 bf16x4 __attribute__((ext_vector_type(4)));
typedef float floatx4 __attribute__((ext_vector_type(4)));

#define LDT 72  // padded LDS leading dim: 144B stride -> <=2-way aliasing on b128 frag reads (free per m136)

// log2(e) / sqrt(64): softmax done in exp2 domain (v_exp_f32 is native 2^x)
#define SM_SCALE_LOG2E 0.18033688011112042f

// global -> LDS async copy, 16B per lane (m97 staging path for the GEMM).
__device__ __forceinline__ void async_copy16(const void* gsrc, void* ldst) {
    __builtin_amdgcn_global_load_lds(
        (const __attribute__((address_space(1))) void*)(uintptr_t)gsrc,
        (__attribute__((address_space(3))) void*)(uintptr_t)ldst, 16, 0, 0);
}

// ---------------------------------------------------------------------------
// Convert fp32 -> bf16 for x(4M), enc(4M), Wq/Wk/Wv(1M each). 2048 elems/block.
// ---------------------------------------------------------------------------
__global__ __launch_bounds__(256)
void cvt5_f32_bf16(const float* __restrict__ x, const float* __restrict__ enc,
                   const float* __restrict__ wq, const float* __restrict__ wk,
                   const float* __restrict__ wv,
                   __bf16* __restrict__ xb, __bf16* __restrict__ eb,
                   __bf16* __restrict__ wqb, __bf16* __restrict__ wkb,
                   __bf16* __restrict__ wvb)
{
    const int bx = blockIdx.x;
    const float* s; __bf16* d; int base;
    if (bx < 2048)      { s = x;   d = xb;  base = bx; }
    else if (bx < 4096) { s = enc; d = eb;  base = bx - 2048; }
    else if (bx < 4608) { s = wq;  d = wqb; base = bx - 4096; }
    else if (bx < 5120) { s = wk;  d = wkb; base = bx - 4608; }
    else                { s = wv;  d = wvb; base = bx - 5120; }
    const size_t off = (size_t)base * 2048 + (size_t)threadIdx.x * 8;
    const float4 a = *(const float4*)(s + off);
    const float4 b = *(const float4*)(s + off + 4);
    bf16x8 o;
    o[0] = (__bf16)a.x; o[1] = (__bf16)a.y; o[2] = (__bf16)a.z; o[3] = (__bf16)a.w;
    o[4] = (__bf16)b.x; o[5] = (__bf16)b.y; o[6] = (__bf16)b.z; o[7] = (__bf16)b.w;
    *(bf16x8*)(d + off) = o;
}

// ---------------------------------------------------------------------------
// Fused QKV GEMM, m97 structure (unchanged from R4; ~220 TF at K=1024,
// R6 restructure target once profiled).
// ---------------------------------------------------------------------------
__global__ __launch_bounds__(256)
void gemm3_bt_bias(const __bf16* __restrict__ xb, const __bf16* __restrict__ eb,
                   const __bf16* __restrict__ wqb, const __bf16* __restrict__ wkb,
                   const __bf16* __restrict__ wvb,
                   const float* __restrict__ bq, const float* __restrict__ bk,
                   const float* __restrict__ bv,
                   __bf16* __restrict__ qo, __bf16* __restrict__ ko,
                   __bf16* __restrict__ vo)
{
    constexpr int K = HID;
    __shared__ __align__(16) __bf16 As[128 * 64];  // unpadded: global_load_lds layout
    __shared__ __align__(16) __bf16 Bs[128 * 64];

    const __bf16* A; const __bf16* W; const float* bias; __bf16* C;
    if (blockIdx.z == 0)      { A = xb; W = wqb; bias = bq; C = qo; }
    else if (blockIdx.z == 1) { A = eb; W = wkb; bias = bk; C = ko; }
    else                      { A = eb; W = wvb; bias = bv; C = vo; }

    const int tid  = threadIdx.x;
    const int wave = tid >> 6;
    const int lane = tid & 63;
    const int l15  = lane & 15;
    const int quad = lane >> 4;
    const int bm = blockIdx.y * 128;
    const int bn = blockIdx.x * 128;
    const int wm = (wave >> 1) * 64;
    const int wn = (wave & 1) * 64;

    floatx4 acc[4][4];
#pragma unroll
    for (int i = 0; i < 4; ++i)
#pragma unroll
        for (int j = 0; j < 4; ++j)
            acc[i][j] = (floatx4)(0.0f);

    const int sr = tid >> 3;
    const int sc = (tid & 7) * 8;

    for (int k0 = 0; k0 < K; k0 += 64) {
#pragma unroll
        for (int p = 0; p < 4; ++p) {
            const int r = p * 32 + sr;
            async_copy16(A + (size_t)(bm + r) * K + k0 + sc,
                         (char*)As + p * 4096 + tid * 16);
            async_copy16(W + (size_t)(bn + r) * K + k0 + sc,
                         (char*)Bs + p * 4096 + tid * 16);
        }
        __syncthreads();
#pragma unroll
        for (int kk = 0; kk < 2; ++kk) {
            const int ko_ = kk * 32 + quad * 8;
            bf16x8 af[4], bfr[4];
#pragma unroll
            for (int i = 0; i < 4; ++i) {
                af[i]  = *(const bf16x8*)(As + (wm + i * 16 + l15) * 64 + ko_);
                bfr[i] = *(const bf16x8*)(Bs + (wn + i * 16 + l15) * 64 + ko_);
            }
#pragma unroll
            for (int mi = 0; mi < 4; ++mi)
#pragma unroll
                for (int ni = 0; ni < 4; ++ni)
                    acc[mi][ni] = __builtin_amdgcn_mfma_f32_16x16x32_bf16(
                        af[mi], bfr[ni], acc[mi][ni], 0, 0, 0);
        }
        __syncthreads();
    }

    const int crow0 = bm + wm + quad * 4;
    const int ccol0 = bn + wn + l15;
#pragma unroll
    for (int ni = 0; ni < 4; ++ni) {
        const int n = ccol0 + ni * 16;
        const float bias_f = bias[n];
#pragma unroll
        for (int mi = 0; mi < 4; ++mi) {
#pragma unroll
            for (int r = 0; r < 4; ++r) {
                const int m = crow0 + mi * 16 + r;
                C[(size_t)m * HID + n] = (__bf16)(acc[mi][ni][r] + bias_f);
            }
        }
    }
}

// ---------------------------------------------------------------------------
// Fallback GEMM (fp32 inputs staged+converted through LDS) for small ws.
// ---------------------------------------------------------------------------
__global__ __launch_bounds__(256)
void gemm_bt_bias_f32in(const float* __restrict__ A,
                        const float* __restrict__ W,
                        const float* __restrict__ bias,
                        __hip_bfloat16* __restrict__ C)
{
    constexpr int K = HID;
    __shared__ __align__(16) __hip_bfloat16 As[128 * LDT];
    __shared__ __align__(16) __hip_bfloat16 Bs[128 * LDT];

    const int tid  = threadIdx.x;
    const int wave = tid >> 6;
    const int lane = tid & 63;
    const int bm = blockIdx.y * 128;
    const int bn = blockIdx.x * 128;
    const int wm = (wave >> 1) * 64;
    const int wn = (wave & 1) * 64;

    floatx4 acc[4][4];
#pragma unroll
    for (int i = 0; i < 4; ++i)
#pragma unroll
        for (int j = 0; j < 4; ++j)
            acc[i][j] = (floatx4)(0.0f);

    const int lr = tid >> 4;
    const int lc = (tid & 15) * 4;

    for (int k0 = 0; k0 < K; k0 += 64) {
#pragma unroll
        for (int qq = 0; qq < 8; ++qq) {
            const int r = lr + qq * 16;
            const float4 a4 = *(const float4*)(A + (size_t)(bm + r) * K + k0 + lc);
            const float4 w4 = *(const float4*)(W + (size_t)(bn + r) * K + k0 + lc);
            bf16x4 av, wv;
            av[0] = (__bf16)a4.x; av[1] = (__bf16)a4.y; av[2] = (__bf16)a4.z; av[3] = (__bf16)a4.w;
            wv[0] = (__bf16)w4.x; wv[1] = (__bf16)w4.y; wv[2] = (__bf16)w4.z; wv[3] = (__bf16)w4.w;
            *(bf16x4*)(As + r * LDT + lc) = av;
            *(bf16x4*)(Bs + r * LDT + lc) = wv;
        }
        __syncthreads();
#pragma unroll
        for (int kk = 0; kk < 2; ++kk) {
            const int krow = kk * 32 + (lane >> 4) * 8;
            const int mrow = wm + (lane & 15);
            const int nrow = wn + (lane & 15);
            bf16x8 af[4], bfr[4];
#pragma unroll
            for (int i = 0; i < 4; ++i) {
                af[i]  = *(const bf16x8*)(As + (mrow + i * 16) * LDT + krow);
                bfr[i] = *(const bf16x8*)(Bs + (nrow + i * 16) * LDT + krow);
            }
#pragma unroll
            for (int mi = 0; mi < 4; ++mi)
#pragma unroll
                for (int ni = 0; ni < 4; ++ni)
                    acc[mi][ni] = __builtin_amdgcn_mfma_f32_16x16x32_bf16(
                        af[mi], bfr[ni], acc[mi][ni], 0, 0, 0);
        }
        __syncthreads();
    }

    const int crow0 = bm + wm + (lane >> 4) * 4;
    const int ccol0 = bn + wn + (lane & 15);
#pragma unroll
    for (int ni = 0; ni < 4; ++ni) {
        const int n = ccol0 + ni * 16;
        const float bias_f = bias[n];
#pragma unroll
        for (int mi = 0; mi < 4; ++mi) {
#pragma unroll
            for (int r = 0; r < 4; ++r) {
                const int m = crow0 + mi * 16 + r;
                C[(size_t)m * HID + n] = __float2bfloat16(acc[mi][ni][r] + bias_f);
            }
        }
    }
}

// ---------------------------------------------------------------------------
// Flash attention v2: 128 q-rows/block (32/wave, 2 m-frag groups), Q in
// registers, double-buffered 64-key K/V tiles with reg prefetch, ONE barrier
// per tile (Ps is wave-private; DS ops are in-order per wave), exp2 softmax.
// grid = 64 bh x 8 t-blocks = 512; block = 256.
// ---------------------------------------------------------------------------
__global__ __launch_bounds__(256)
void attn_flash_mfma_v2(const __bf16* __restrict__ q,
                        const __bf16* __restrict__ k,
                        const __bf16* __restrict__ v,
                        float* __restrict__ out)
{
    __shared__ __align__(16) __bf16 Ks[2][64 * LDT];    // [n][d]
    __shared__ __align__(16) __bf16 Vt[2][64 * LDT];    // [d][n]
    __shared__ __align__(16) __bf16 Ps[4][32 * LDT];    // per-wave P [qrow32][n]

    const int tid  = threadIdx.x;
    const int wave = tid >> 6;
    const int lane = tid & 63;
    const int l15  = lane & 15;
    const int quad = lane >> 4;

    const int bx = blockIdx.x;           // 512 blocks
    const int bt = 7 - (bx & 7);         // longest-job-first over 128-row t-blocks
    const int bh = bx >> 3;              // 0..63
    const int h  = bh & (NHEADS - 1);
    const int b  = bh >> 4;
    const int t0 = bt * 128;

    const __bf16* kbase = k + (size_t)b * N_SZ * HID + h * DHEAD;
    const __bf16* vbase = v + (size_t)b * N_SZ * HID + h * DHEAD;

    // ---- Q fragments directly to registers ----
    // A-frag: m = l15 (row g*16+l15 of wave's 32), k = kk*32 + quad*8 + j
    bf16x8 aq[2][2];
    {
        const __bf16* qb = q + (size_t)(b * T_SZ + t0 + wave * 32) * HID + h * DHEAD;
#pragma unroll
        for (int g = 0; g < 2; ++g)
#pragma unroll
            for (int kk = 0; kk < 2; ++kk)
                aq[g][kk] = *(const bf16x8*)(qb + (size_t)(g * 16 + l15) * HID
                                             + kk * 32 + quad * 8);
    }

    // staging index helpers
    const int kr = tid >> 3;             // K: 32 rows/pass
    const int kc = (tid & 7) * 8;
    const int vn = tid & 63;             // V: transposed scatter
    const int vd = (tid >> 6) * 8;

    // ---- prologue: stage tile 0 into buffer 0 ----
#pragma unroll
    for (int p = 0; p < 2; ++p) {
        *(bf16x8*)(&Ks[0][(kr + p * 32) * LDT + kc]) =
            *(const bf16x8*)(kbase + (size_t)(kr + p * 32) * HID + kc);
        const bf16x8 vv = *(const bf16x8*)(vbase + (size_t)vn * HID + vd + p * 32);
#pragma unroll
        for (int j = 0; j < 8; ++j)
            Vt[0][(vd + p * 32 + j) * LDT + vn] = vv[j];
    }
    __syncthreads();

    // online-softmax state: rows = wave*32 + g*16 + quad*4 + r
    float mrun[2][4], lrun[2][4];
    floatx4 oacc[2][4];
#pragma unroll
    for (int g = 0; g < 2; ++g)
#pragma unroll
        for (int r = 0; r < 4; ++r) { mrun[g][r] = -INFINITY; lrun[g][r] = 0.f; }
#pragma unroll
    for (int g = 0; g < 2; ++g)
#pragma unroll
        for (int nd = 0; nd < 4; ++nd) oacc[g][nd] = (floatx4)(0.0f);

    __bf16* pw = &Ps[wave][0];
    const int ntiles = 2 * bt + 2;

    for (int it = 0; it < ntiles; ++it) {
        const int bi = it & 1;
        const int n0 = it * 64;

        // ---- prefetch next K/V tile into registers (in flight across compute) ----
        bf16x8 nk0, nk1, nv0, nv1;
        const bool pf = (it + 1 < ntiles);
        if (pf) {
            const int nn0 = n0 + 64;
            nk0 = *(const bf16x8*)(kbase + (size_t)(nn0 + kr) * HID + kc);
            nk1 = *(const bf16x8*)(kbase + (size_t)(nn0 + kr + 32) * HID + kc);
            nv0 = *(const bf16x8*)(vbase + (size_t)(nn0 + vn) * HID + vd);
            nv1 = *(const bf16x8*)(vbase + (size_t)(nn0 + vn) * HID + vd + 32);
        }

        // ---- S = Q @ K^T : 16 MFMAs ----
        floatx4 sacc[2][4];
#pragma unroll
        for (int g = 0; g < 2; ++g)
#pragma unroll
            for (int ni = 0; ni < 4; ++ni) sacc[g][ni] = (floatx4)(0.0f);
        const __bf16* ksb = &Ks[bi][0];
#pragma unroll
        for (int kk = 0; kk < 2; ++kk) {
            const int ko = kk * 32 + quad * 8;
#pragma unroll
            for (int ni = 0; ni < 4; ++ni) {
                const bf16x8 bk = *(const bf16x8*)(ksb + (ni * 16 + l15) * LDT + ko);
                sacc[0][ni] = __builtin_amdgcn_mfma_f32_16x16x32_bf16(aq[0][kk], bk, sacc[0][ni], 0, 0, 0);
                sacc[1][ni] = __builtin_amdgcn_mfma_f32_16x16x32_bf16(aq[1][kk], bk, sacc[1][ni], 0, 0, 0);
            }
        }

        // ---- scale to exp2 domain + mask (last two tiles) + row max ----
        const bool msk = (it >= 2 * bt);
        float rmax[2][4];
#pragma unroll
        for (int g = 0; g < 2; ++g)
#pragma unroll
            for (int r = 0; r < 4; ++r) rmax[g][r] = -INFINITY;
#pragma unroll
        for (int g = 0; g < 2; ++g)
#pragma unroll
            for (int ni = 0; ni < 4; ++ni)
#pragma unroll
                for (int r = 0; r < 4; ++r) {
                    float tv = sacc[g][ni][r] * SM_SCALE_LOG2E;
                    if (msk) {
                        const int col = n0 + ni * 16 + l15;
                        const int row = t0 + wave * 32 + g * 16 + quad * 4 + r;
                        if (col > row) tv = -INFINITY;
                    }
                    sacc[g][ni][r] = tv;
                    rmax[g][r] = fmaxf(rmax[g][r], tv);
                }
#pragma unroll
        for (int off = 1; off < 16; off <<= 1)
#pragma unroll
            for (int g = 0; g < 2; ++g)
#pragma unroll
                for (int r = 0; r < 4; ++r)
                    rmax[g][r] = fmaxf(rmax[g][r], __shfl_xor(rmax[g][r], off, 64));

        // ---- online update ----
        float alpha[2][4], rsum[2][4];
#pragma unroll
        for (int g = 0; g < 2; ++g)
#pragma unroll
            for (int r = 0; r < 4; ++r) {
                const float mnew = fmaxf(mrun[g][r], rmax[g][r]);
                alpha[g][r] = exp2f(mrun[g][r] - mnew);   // exp2(-inf)=0 first tile
                mrun[g][r]  = mnew;
                rsum[g][r]  = 0.f;
            }
#pragma unroll
        for (int g = 0; g < 2; ++g)
#pragma unroll
            for (int ni = 0; ni < 4; ++ni)
#pragma unroll
                for (int r = 0; r < 4; ++r) {
                    const float p = exp2f(sacc[g][ni][r] - mrun[g][r]);
                    rsum[g][r] += p;
                    pw[(g * 16 + quad * 4 + r) * LDT + ni * 16 + l15] = (__bf16)p;
                }
#pragma unroll
        for (int off = 1; off < 16; off <<= 1)
#pragma unroll
            for (int g = 0; g < 2; ++g)
#pragma unroll
                for (int r = 0; r < 4; ++r)
                    rsum[g][r] += __shfl_xor(rsum[g][r], off, 64);
#pragma unroll
        for (int g = 0; g < 2; ++g)
#pragma unroll
            for (int r = 0; r < 4; ++r)
                lrun[g][r] = lrun[g][r] * alpha[g][r] + rsum[g][r];
#pragma unroll
        for (int g = 0; g < 2; ++g)
#pragma unroll
            for (int nd = 0; nd < 4; ++nd)
#pragma unroll
                for (int r = 0; r < 4; ++r)
                    oacc[g][nd][r] *= alpha[g][r];

        // no barrier: Ps is wave-private; per-wave DS ops are in-order

        // ---- O += P @ V : 16 MFMAs ----
        const __bf16* vtb = &Vt[bi][0];
#pragma unroll
        for (int kk = 0; kk < 2; ++kk) {
            const int ko = kk * 32 + quad * 8;
            const bf16x8 ap0 = *(const bf16x8*)(pw + l15 * LDT + ko);
            const bf16x8 ap1 = *(const bf16x8*)(pw + (16 + l15) * LDT + ko);
#pragma unroll
            for (int nd = 0; nd < 4; ++nd) {
                const bf16x8 bvv = *(const bf16x8*)(vtb + (nd * 16 + l15) * LDT + ko);
                oacc[0][nd] = __builtin_amdgcn_mfma_f32_16x16x32_bf16(ap0, bvv, oacc[0][nd], 0, 0, 0);
                oacc[1][nd] = __builtin_amdgcn_mfma_f32_16x16x32_bf16(ap1, bvv, oacc[1][nd], 0, 0, 0);
            }
        }

        // ---- write prefetched tile into the other buffer ----
        if (pf) {
            const int wb = bi ^ 1;
            *(bf16x8*)(&Ks[wb][kr * LDT + kc]) = nk0;
            *(bf16x8*)(&Ks[wb][(kr + 32) * LDT + kc]) = nk1;
#pragma unroll
            for (int j = 0; j < 8; ++j) {
                Vt[wb][(vd + j) * LDT + vn] = nv0[j];
                Vt[wb][(vd + 32 + j) * LDT + vn] = nv1[j];
            }
        }
        __syncthreads();   // single barrier per tile
    }

    // ---- epilogue ----
#pragma unroll
    for (int g = 0; g < 2; ++g) {
        float invl[4];
#pragma unroll
        for (int r = 0; r < 4; ++r) invl[r] = 1.0f / lrun[g][r];
#pragma unroll
        for (int nd = 0; nd < 4; ++nd)
#pragma unroll
            for (int r = 0; r < 4; ++r) {
                const int trow = t0 + wave * 32 + g * 16 + quad * 4 + r;
                out[(size_t)(b * T_SZ + trow) * HID + h * DHEAD + nd * 16 + l15] =
                    oacc[g][nd][r] * invl[r];
            }
    }
}

extern "C" void kernel_launch(void* const* d_in, const int* in_sizes, int n_in,
                              void* d_out, int out_size, void* d_ws, size_t ws_size,
                              hipStream_t stream) {
    const float* x   = (const float*)d_in[0];
    const float* enc = (const float*)d_in[1];
    const float* Wq  = (const float*)d_in[2];
    const float* bq  = (const float*)d_in[3];
    const float* Wk  = (const float*)d_in[4];
    const float* bk  = (const float*)d_in[5];
    const float* Wv  = (const float*)d_in[6];
    const float* bv  = (const float*)d_in[7];
    float* out = (float*)d_out;

    char* ws = (char*)d_ws;
    const size_t MiB = 1024 * 1024;
    __bf16* q_ws = (__bf16*)(ws);
    __bf16* k_ws = (__bf16*)(ws + 8 * MiB);
    __bf16* v_ws = (__bf16*)(ws + 16 * MiB);

    const dim3 blk(256);
    if (ws_size >= 46 * MiB) {
        __bf16* xb  = (__bf16*)(ws + 24 * MiB);
        __bf16* eb  = (__bf16*)(ws + 32 * MiB);
        __bf16* wqb = (__bf16*)(ws + 40 * MiB);
        __bf16* wkb = (__bf16*)(ws + 42 * MiB);
        __bf16* wvb = (__bf16*)(ws + 44 * MiB);
        cvt5_f32_bf16<<<dim3(5632), blk, 0, stream>>>(x, enc, Wq, Wk, Wv,
                                                      xb, eb, wqb, wkb, wvb);
        gemm3_bt_bias<<<dim3(8, 32, 3), blk, 0, stream>>>(
            xb, eb, wqb, wkb, wvb, bq, bk, bv, q_ws, k_ws, v_ws);
    } else {
        const dim3 gg(HID / 128, (B_SZ * T_SZ) / 128);
        gemm_bt_bias_f32in<<<gg, blk, 0, stream>>>(x,   Wq, bq, (__hip_bfloat16*)q_ws);
        gemm_bt_bias_f32in<<<gg, blk, 0, stream>>>(enc, Wk, bk, (__hip_bfloat16*)k_ws);
        gemm_bt_bias_f32in<<<gg, blk, 0, stream>>>(enc, Wv, bv, (__hip_bfloat16*)v_ws);
    }

    attn_flash_mfma_v2<<<dim3(512), blk, 0, stream>>>(q_ws, k_ws, v_ws, out);
}